// Round 10
// baseline (682.466 us; speedup 1.0000x reference)
//
#include <hip/hip_runtime.h>
#include <hip/hip_bf16.h>

#define B_ 256
#define T_ 512
#define I_ 128
#define H_ 256

typedef __bf16 bf16x8 __attribute__((ext_vector_type(8)));
typedef float  f32x4  __attribute__((ext_vector_type(4)));
typedef unsigned short u16;
typedef unsigned int   u32;

union U16x8Cast { uint4 v; bf16x8 b; };

__device__ inline u16 f2b(float f) {           // fp32 -> bf16 bits (RNE)
    union { __bf16 h; u16 u; } c; c.h = (__bf16)f; return c.u;
}
__device__ inline bf16x8 pack8(float4 lo, float4 hi) {
    bf16x8 f;
    f[0]=(__bf16)lo.x; f[1]=(__bf16)lo.y; f[2]=(__bf16)lo.z; f[3]=(__bf16)lo.w;
    f[4]=(__bf16)hi.x; f[5]=(__bf16)hi.y; f[6]=(__bf16)hi.z; f[7]=(__bf16)hi.w;
    return f;
}
__device__ inline uint2 pack4(float a, float b, float c, float d) {
    uint2 p;
    p.x = (u32)f2b(a) | ((u32)f2b(b) << 16);
    p.y = (u32)f2b(c) | ((u32)f2b(d) << 16);
    return p;
}
__device__ inline f32x4 b4_to_f32x4(uint2 u) {
    f32x4 r;
    r[0] = __uint_as_float(u.x << 16);
    r[1] = __uint_as_float(u.x & 0xFFFF0000u);
    r[2] = __uint_as_float(u.y << 16);
    r[3] = __uint_as_float(u.y & 0xFFFF0000u);
    return r;
}
// tanh(x) = 1 - 2/(1+e^{2x}); v_rcp (±1 ulp) beats the precise-div sequence.
__device__ inline float fast_tanh(float x) {
    float e = __expf(2.f * x);
    float d = 1.f + e;
    float r;
    asm("v_rcp_f32 %0, %1" : "=v"(r) : "v"(d));
    return fmaf(-2.f, r, 1.f);
}

// LDS-drain-only workgroup barrier: no vmcnt drain -> global prefetches
// stay in flight across the barrier (proven win, R8: -46% scan time).
#define WG_BARRIER() asm volatile("s_waitcnt lgkmcnt(0)\n\ts_barrier" ::: "memory")

// Agent-scope acquire gate: spin until done-counter hits 16, then fence so
// cross-XCD xw writes are visible to plain loads (R7-proven protocol).
__device__ inline void spin_done(const u32* p) {
    while (__hip_atomic_load(p, __ATOMIC_RELAXED, __HIP_MEMORY_SCOPE_AGENT) < 16u)
        __builtin_amdgcn_s_sleep(8);
    __threadfence();
}

#define LDST 264   // u16 stride of gemm LDS tile row (528 B)

// =====================================================================
// ONE persistent kernel, 256 WGs x 512 threads, __launch_bounds__(512,1).
// Register pressure >128 (worker path ~150 VGPR+AGPR) => a 512-thr WG
// needs 2 waves/SIMD at <=256 regs => EXACTLY 1 WG/CU. This is the R7
// fusion minus R7's fatal flaw (launch_bounds(512,2) allowed 2 WG/CU ->
// workers time-shared the scan's CUs).
//   WG 0..15   : R8-structure scan (lgkm barrier + pfA/pfB 2-step
//                prefetch + v_rcp tanh) + split MFMA chains; gated on
//                done counters at t-block boundaries (4 gates total).
//   WG 16..255 : R7 worker loop; t-major tickets (tb0 first); agent-scope
//                release publish.
// ctrl (zeroed): [0]=ticket; +16: done[64] x16-padded, idx (tb*16+g)*16.
// =====================================================================
__global__ __launch_bounds__(512, 1) void fused_rnn(const float* __restrict__ x,
                                                    const float* __restrict__ W_ih,
                                                    const float* __restrict__ W_hh,
                                                    const float* __restrict__ b_ih,
                                                    const float* __restrict__ b_hh,
                                                    const float* __restrict__ fc_w,
                                                    const float* __restrict__ fc_b,
                                                    float* __restrict__ out,
                                                    u32* __restrict__ ctrl,
                                                    u16* __restrict__ xw) {
    __shared__ __attribute__((aligned(16))) u16 lds[64 * LDST];  // 33.8 KB shared by both paths
    __shared__ u32 tkt;

    const int tid  = (int)threadIdx.x;
    const int wave = tid >> 6;       // 0..7
    const int lane = tid & 63;
    const int q    = lane >> 4;
    const int ml   = lane & 15;

    u32* ctr  = ctrl;
    u32* done = ctrl + 16;           // 64 entries, x16 padded

    const size_t tstride = (size_t)B_ * H_;

    if (blockIdx.x < 16) {
        // ================= SCAN (R8 structure + gates + split chains) =================
        u16 (*hbuf)[4096] = (u16(*)[4096])lds;            // 2 x 8 KB
        float (*red)[16]  = (float(*)[16])(lds + 8192);   // byte 16384
        const int g  = (int)blockIdx.x;
        const int b0 = g * 16;
        const int m  = ml;

        // W_hh A-frags: lane holds W_hh[n = wave*32+tau2*16+m][k = kap*32+q*8+0..7]
        bf16x8 wf[2][8];
#pragma unroll
        for (int tau2 = 0; tau2 < 2; ++tau2) {
            const float* wr = W_hh + (size_t)(wave * 32 + tau2 * 16 + m) * H_;
#pragma unroll
            for (int kap = 0; kap < 8; ++kap) {
                const int k0 = kap * 32 + q * 8;
                wf[tau2][kap] = pack8(*(const float4*)(wr + k0), *(const float4*)(wr + k0 + 4));
            }
        }

        // LDS write indices (u16 units) for C -> B-frag relayout
        int widx[2];
#pragma unroll
        for (int tau2 = 0; tau2 < 2; ++tau2) {
            const int nbw = wave * 32 + tau2 * 16 + q * 4;
            widx[tau2] = (nbw >> 5) * 512 + (((nbw >> 3) & 3) * 16 + m) * 8 + (nbw & 7);
        }

        {   // zero h buffer 0 (8 KB = 512 uint4)
            uint4* p = (uint4*)&hbuf[0][0];
            const uint4 z = {0u, 0u, 0u, 0u};
            p[tid] = z;
        }
        WG_BARRIER();

        spin_done(&done[(0 * 16 + g) * 16]);              // t-block 0 ready

        const u16* xwp = xw + (size_t)(b0 + m) * H_ + (wave * 32 + q * 4);

        uint2 pfA[2], pfB[2];                             // alternating, never copied
        pfA[0] = *(const uint2*)(xwp);
        pfA[1] = *(const uint2*)(xwp + 16);
        pfB[0] = *(const uint2*)(xwp + tstride);
        pfB[1] = *(const uint2*)(xwp + tstride + 16);

        int cur = 0;
        f32x4 accM[2];
        for (int tt = 0; tt < T_ / 2; ++tt) {
            // ---------- step A: t = 2*tt (even, never last) ----------
            {
                const int t = 2 * tt;
                f32x4 accA[2], accB[2];
                accA[0] = b4_to_f32x4(pfA[0]);
                accA[1] = b4_to_f32x4(pfA[1]);
                accB[0] = (f32x4)0.f;
                accB[1] = (f32x4)0.f;
                if (t + 2 < T_) {                         // reload pfA for t+2
                    if (((t + 2) & 127) == 0)             // t-block boundary gate
                        spin_done(&done[(((t + 2) >> 7) * 16 + g) * 16]);
                    const u16* pt = xwp + (size_t)(t + 2) * tstride;
                    pfA[0] = *(const uint2*)(pt);
                    pfA[1] = *(const uint2*)(pt + 16);
                }
                const uint4* hb = (const uint4*)&hbuf[cur][0];
#pragma unroll
                for (int kap = 0; kap < 4; ++kap) {       // 4 indep depth-4 chains
                    U16x8Cast cA; cA.v = hb[kap * 64 + lane];
                    U16x8Cast cB; cB.v = hb[(kap + 4) * 64 + lane];
                    accA[0] = __builtin_amdgcn_mfma_f32_16x16x32_bf16(wf[0][kap],     cA.b, accA[0], 0, 0, 0);
                    accA[1] = __builtin_amdgcn_mfma_f32_16x16x32_bf16(wf[1][kap],     cA.b, accA[1], 0, 0, 0);
                    accB[0] = __builtin_amdgcn_mfma_f32_16x16x32_bf16(wf[0][kap + 4], cB.b, accB[0], 0, 0, 0);
                    accB[1] = __builtin_amdgcn_mfma_f32_16x16x32_bf16(wf[1][kap + 4], cB.b, accB[1], 0, 0, 0);
                }
                accM[0] = accA[0] + accB[0];
                accM[1] = accA[1] + accB[1];
                u16* wb = &hbuf[cur ^ 1][0];
#pragma unroll
                for (int tau2 = 0; tau2 < 2; ++tau2) {
                    uint2 pk = pack4(fast_tanh(accM[tau2][0]), fast_tanh(accM[tau2][1]),
                                     fast_tanh(accM[tau2][2]), fast_tanh(accM[tau2][3]));
                    *(uint2*)(wb + widx[tau2]) = pk;
                }
                WG_BARRIER();
                cur ^= 1;
            }
            // ---------- step B: t = 2*tt+1 (t = T_-1 on the last iter) ----------
            {
                const int t = 2 * tt + 1;
                f32x4 accA[2], accB[2];
                accA[0] = b4_to_f32x4(pfB[0]);
                accA[1] = b4_to_f32x4(pfB[1]);
                accB[0] = (f32x4)0.f;
                accB[1] = (f32x4)0.f;
                if (t + 2 < T_) {                         // reload pfB for t+2 (odd: never a gate)
                    const u16* pt = xwp + (size_t)(t + 2) * tstride;
                    pfB[0] = *(const uint2*)(pt);
                    pfB[1] = *(const uint2*)(pt + 16);
                }
                const uint4* hb = (const uint4*)&hbuf[cur][0];
#pragma unroll
                for (int kap = 0; kap < 4; ++kap) {
                    U16x8Cast cA; cA.v = hb[kap * 64 + lane];
                    U16x8Cast cB; cB.v = hb[(kap + 4) * 64 + lane];
                    accA[0] = __builtin_amdgcn_mfma_f32_16x16x32_bf16(wf[0][kap],     cA.b, accA[0], 0, 0, 0);
                    accA[1] = __builtin_amdgcn_mfma_f32_16x16x32_bf16(wf[1][kap],     cA.b, accA[1], 0, 0, 0);
                    accB[0] = __builtin_amdgcn_mfma_f32_16x16x32_bf16(wf[0][kap + 4], cB.b, accB[0], 0, 0, 0);
                    accB[1] = __builtin_amdgcn_mfma_f32_16x16x32_bf16(wf[1][kap + 4], cB.b, accB[1], 0, 0, 0);
                }
                accM[0] = accA[0] + accB[0];
                accM[1] = accA[1] + accB[1];
                if (t != T_ - 1) {                        // last h feeds fc only
                    u16* wb = &hbuf[cur ^ 1][0];
#pragma unroll
                    for (int tau2 = 0; tau2 < 2; ++tau2) {
                        uint2 pk = pack4(fast_tanh(accM[tau2][0]), fast_tanh(accM[tau2][1]),
                                         fast_tanh(accM[tau2][2]), fast_tanh(accM[tau2][3]));
                        *(uint2*)(wb + widx[tau2]) = pk;
                    }
                    WG_BARRIER();
                    cur ^= 1;
                }
            }
        }

        // fc head: out[b] = sum_n tanh(h)[n] * fc_w[n] + fc_b
        float4 fcw[2];
#pragma unroll
        for (int tau2 = 0; tau2 < 2; ++tau2)
            fcw[tau2] = *(const float4*)(fc_w + wave * 32 + tau2 * 16 + q * 4);

        float partial = 0.f;
#pragma unroll
        for (int tau2 = 0; tau2 < 2; ++tau2) {
            partial += fast_tanh(accM[tau2][0]) * fcw[tau2].x;
            partial += fast_tanh(accM[tau2][1]) * fcw[tau2].y;
            partial += fast_tanh(accM[tau2][2]) * fcw[tau2].z;
            partial += fast_tanh(accM[tau2][3]) * fcw[tau2].w;
        }
        partial += __shfl_xor(partial, 16);
        partial += __shfl_xor(partial, 32);
        __syncthreads();
        if (lane < 16) red[wave][m] = partial;
        __syncthreads();
        if (tid < 16) {
            float s = red[0][tid] + red[1][tid] + red[2][tid] + red[3][tid]
                    + red[4][tid] + red[5][tid] + red[6][tid] + red[7][tid];
            out[b0 + tid] = s + fc_b[0];
        }
    } else {
        // ================= GEMM workers (R7-proven loop) =================
        const int n0w = wave * 32;

        bf16x8 wA[2][4];
#pragma unroll
        for (int tau2 = 0; tau2 < 2; ++tau2) {
            const float* wr = W_ih + (size_t)(n0w + tau2 * 16 + ml) * I_;
#pragma unroll
            for (int kap = 0; kap < 4; ++kap) {
                const int k0 = kap * 32 + q * 8;
                wA[tau2][kap] = pack8(*(const float4*)(wr + k0), *(const float4*)(wr + k0 + 4));
            }
        }
        float4 bias4[2];
#pragma unroll
        for (int tau2 = 0; tau2 < 2; ++tau2) {
            const int n = n0w + tau2 * 16 + q * 4;
            float4 bi = *(const float4*)(b_ih + n);
            float4 bh = *(const float4*)(b_hh + n);
            bias4[tau2] = make_float4(bi.x + bh.x, bi.y + bh.y, bi.z + bh.z, bi.w + bh.w);
        }

        for (;;) {
            if (tid == 0) tkt = atomicAdd(ctr, 1u);
            __syncthreads();
            const u32 ticket = tkt;
            __syncthreads();
            if (ticket >= 1024u) break;

            const int tb = (int)(ticket >> 8);            // t-block 0..3 (t-major)
            const int bb = (int)(ticket & 255u);          // batch row
            const int m0 = bb * T_ + tb * 128;            // x row base

            f32x4 acc[8][2];
#pragma unroll
            for (int mt = 0; mt < 8; ++mt) { acc[mt][0] = (f32x4)0.f; acc[mt][1] = (f32x4)0.f; }

#pragma unroll
            for (int kap = 0; kap < 4; ++kap) {
                bf16x8 xB[8];
#pragma unroll
                for (int mt = 0; mt < 8; ++mt) {
                    const float* xr = x + (size_t)(m0 + mt * 16 + ml) * I_ + kap * 32 + q * 8;
                    xB[mt] = pack8(*(const float4*)xr, *(const float4*)(xr + 4));
                }
#pragma unroll
                for (int mt = 0; mt < 8; ++mt) {
                    acc[mt][0] = __builtin_amdgcn_mfma_f32_16x16x32_bf16(wA[0][kap], xB[mt], acc[mt][0], 0, 0, 0);
                    acc[mt][1] = __builtin_amdgcn_mfma_f32_16x16x32_bf16(wA[1][kap], xB[mt], acc[mt][1], 0, 0, 0);
                }
            }

            // Epilogue: 2 passes of 64 t-rows through LDS, coalesced out.
#pragma unroll
            for (int p = 0; p < 2; ++p) {
                if (p) __syncthreads();
#pragma unroll
                for (int mt = 0; mt < 4; ++mt) {
                    const int row = mt * 16 + ml;         // local t-row (C col = ml)
                    const int mg  = p * 4 + mt;
#pragma unroll
                    for (int tau2 = 0; tau2 < 2; ++tau2) {
                        uint2 pk = pack4(acc[mg][tau2][0] + bias4[tau2].x,
                                         acc[mg][tau2][1] + bias4[tau2].y,
                                         acc[mg][tau2][2] + bias4[tau2].z,
                                         acc[mg][tau2][3] + bias4[tau2].w);
                        *(uint2*)(lds + row * LDST + n0w + tau2 * 16 + q * 4) = pk;
                    }
                }
                __syncthreads();
#pragma unroll
                for (int s = 0; s < 2; ++s) {
                    const int rr = s * 32 + (tid >> 4);   // 0..63
                    const int c  = tid & 15;
                    const uint4* srcp = (const uint4*)(lds + rr * LDST);
                    uint4* dstp = (uint4*)(xw + ((size_t)(tb * 128 + p * 64 + rr) * B_ + bb) * H_);
                    uint4 v0 = srcp[c];
                    uint4 v1 = srcp[c + 16];
                    dstp[c] = v0;
                    dstp[c + 16] = v1;
                }
            }

            __threadfence();                              // release: drain stores
            __syncthreads();
            if (tid == 0)
                __hip_atomic_fetch_add(&done[(tb * 16 + (bb >> 4)) * 16], 1u,
                                       __ATOMIC_RELEASE, __HIP_MEMORY_SCOPE_AGENT);
            __syncthreads();                              // lds reuse hazard
        }
    }
}

// =====================================================================
extern "C" void kernel_launch(void* const* d_in, const int* in_sizes, int n_in,
                              void* d_out, int out_size, void* d_ws, size_t ws_size,
                              hipStream_t stream) {
    const float* x    = (const float*)d_in[0];
    const float* W_ih = (const float*)d_in[1];
    const float* W_hh = (const float*)d_in[2];
    const float* b_ih = (const float*)d_in[3];
    const float* b_hh = (const float*)d_in[4];
    const float* fc_w = (const float*)d_in[5];
    const float* fc_b = (const float*)d_in[6];
    float* out = (float*)d_out;

    // ws: [ctrl: 8 KB (zeroed)][xw bf16 [T][B][H]: 64 MB]
    u32* ctrl  = (u32*)d_ws;
    u16* xwbuf = (u16*)((char*)d_ws + 8192);

    hipMemsetAsync(d_ws, 0, 8192, stream);
    fused_rnn<<<256, 512, 0, stream>>>(x, W_ih, W_hh, b_ih, b_hh, fc_w, fc_b,
                                       out, ctrl, xwbuf);
}